// Round 10
// baseline (141.020 us; speedup 1.0000x reference)
//
#include <hip/hip_runtime.h>

// Problem: B=8, L=2048, H=256. fp32 in/out.
#define B_ 8
#define L_ 2048
#define H_ 256

typedef _Float16 half8 __attribute__((ext_vector_type(8)));
typedef _Float16 half4_t __attribute__((ext_vector_type(4)));
typedef float f32x4 __attribute__((ext_vector_type(4)));

__device__ __forceinline__ float fast_tanh(float x) {
    const float e2 = __expf(2.f * x);
    return 1.f - 2.f * __builtin_amdgcn_rcpf(e2 + 1.f);
}

// raw barrier: LDS-visibility only (lgkm drain), vmcnt stays in flight.
// Hardened form: the empty "memory" asm after s_barrier pins memory ops on
// their side of the barrier (strictly MORE conservative than R5's passing
// macro — cannot introduce a race, only forbid reorderings).
#define PHASE_BARRIER() do {                                   \
        asm volatile("s_waitcnt lgkmcnt(0)" ::: "memory");     \
        __builtin_amdgcn_s_barrier();                          \
        asm volatile("" ::: "memory");                         \
        __builtin_amdgcn_sched_barrier(0);                     \
    } while (0)

// ---------------------------------------------------------------------------
// prep (R4/R5 verbatim — passing): one block = 64 rows of text (mat=0) or
// opin (mat=1). w_lds double-buffered, pinned W prefetch, raw barriers,
// vtg emitted in MFMA-fragment-tiled layout [b][kc][ks][q4][h][j8].
// ---------------------------------------------------------------------------
__global__ __launch_bounds__(256, 2) void prep_kernel(
    const float* __restrict__ opin, const float* __restrict__ text,
    const int* __restrict__ pos_ids,
    const float* __restrict__ Wt, const float* __restrict__ bt,
    const float* __restrict__ Wo, const float* __restrict__ wa,
    const float* __restrict__ ba,
    float* __restrict__ ws_st, float2* __restrict__ ws_cm,
    _Float16* __restrict__ vtg)
{
    __shared__ __align__(16) _Float16 a_lds[4][8][512];     // 32 KB
    __shared__ __align__(16) _Float16 w_lds[2][16][512];    // 32 KB double-buffered

    const int tid  = threadIdx.x;
    const int lane = tid & 63;
    const int rg   = tid >> 6;
    const int mat  = blockIdx.x & 1;
    const size_t g0 = (size_t)(blockIdx.x >> 1) * 64;

    const float* __restrict__ src = mat ? opin : text;
    const float* __restrict__ W   = mat ? Wo   : Wt;

    f32x4 wregA[8], wregB[8];
#define ISSUE_W(DST, KC) do {                                                   \
        _Pragma("unroll")                                                       \
        for (int p = 0; p < 8; ++p) {                                           \
            const float* p_ = W + (p * 32 + (tid >> 3)) * 256 + (KC) * 32 +     \
                              (tid & 7) * 4;                                    \
            asm volatile("global_load_dwordx4 %0, %1, off"                      \
                         : "=v"(DST[p]) : "v"(p_));                             \
        }                                                                       \
    } while (0)

    ISSUE_W(wregA, 0);

    for (int v = 0; v < 16; ++v) {
        const int idx = v * 256 + tid;
        const int row = idx >> 6;
        const int k   = (idx & 63) * 4;
        const float4 f = *(const float4*)(src + (g0 + row) * 256 + k);
        half4_t h = { (_Float16)f.x, (_Float16)f.y, (_Float16)f.z, (_Float16)f.w };
        const int off = ((row & 15) + 16 * ((k >> 3) & 3)) * 8 + (k & 7);
        *(half4_t*)&a_lds[row >> 4][k >> 5][off] = h;
    }
    PHASE_BARRIER();

    f32x4 acc[16];
#pragma unroll
    for (int nt = 0; nt < 16; ++nt) acc[nt] = (f32x4){0.f, 0.f, 0.f, 0.f};

    auto wbody = [&](const int kc, f32x4 (&cur)[8], f32x4 (&nxt)[8]) {
        asm volatile("s_waitcnt vmcnt(0)" ::: "memory");
        __builtin_amdgcn_sched_barrier(0);
        if (kc < 7) ISSUE_W(nxt, kc + 1);
#pragma unroll
        for (int p = 0; p < 8; ++p) {
            const int n = p * 32 + (tid >> 3);
            const int k = (tid & 7) * 4;
            const float4 f = __builtin_bit_cast(float4, cur[p]);
            half4_t h = { (_Float16)f.x, (_Float16)f.y, (_Float16)f.z, (_Float16)f.w };
            const int off = ((n & 15) + 16 * (k >> 3)) * 8 + (k & 7);
            *(half4_t*)&w_lds[kc & 1][n >> 4][off] = h;
        }
        PHASE_BARRIER();
        const half8 afrag = *(const half8*)&a_lds[rg][kc][lane * 8];
#pragma unroll
        for (int nt = 0; nt < 16; ++nt) {
            const half8 bfrag = *(const half8*)&w_lds[kc & 1][nt][lane * 8];
            acc[nt] = __builtin_amdgcn_mfma_f32_16x16x32_f16(afrag, bfrag, acc[nt], 0, 0, 0);
        }
    };
    for (int kc = 0; kc < 8; kc += 2) {
        wbody(kc,     wregA, wregB);
        wbody(kc + 1, wregB, wregA);
    }
#undef ISSUE_W

    const int em = lane & 15, q = lane >> 4;
    float rowsum[4] = {0.f, 0.f, 0.f, 0.f};
#pragma unroll
    for (int nt = 0; nt < 16; ++nt) {
        const int col  = nt * 16 + em;
        const float btv = mat ? 0.f : bt[col];
        const float wav = wa[mat * 256 + col];
#pragma unroll
        for (int r = 0; r < 4; ++r)
            rowsum[r] += fast_tanh(acc[nt][r] + btv) * wav;
    }
#pragma unroll
    for (int r = 0; r < 4; ++r) {
        float s = rowsum[r];
        s += __shfl_xor(s, 1, 64);
        s += __shfl_xor(s, 2, 64);
        s += __shfl_xor(s, 4, 64);
        s += __shfl_xor(s, 8, 64);
        if (em == 0) {
            const size_t grow = g0 + rg * 16 + q * 4 + r;
            if (mat == 0) {
                ws_st[grow] = s;
            } else {
                const int p = pos_ids[grow];
                const bool isop = (p==19)|(p==20)|(p==21)|(p==33)|(p==34)|(p==35)|((p>=41)&(p<=46));
                const float mult = isop ? 8.f : 1.f;
                const float c = s + ba[0];
                ws_cm[grow] = make_float2(c * mult, mult);
            }
        }
    }

    if (mat == 1) {
        const int h = tid;
        const size_t b = g0 >> 11;
        const int kcj = (int)((g0 & 2047) >> 6);
        const int kc = h >> 5, kq = (h >> 3) & 3, jh = h & 7;
        _Float16 vals[64];
#pragma unroll
        for (int r = 0; r < 64; ++r)
            vals[r] = a_lds[r >> 4][kc][((r & 15) + 16 * kq) * 8 + jh];
        _Float16* dst = vtg + ((size_t)b * 32 + kcj) * 16384 + h * 8;
#pragma unroll
        for (int w = 0; w < 8; ++w)
            *(half8*)(dst + w * 2048) = *(half8*)&vals[w * 8];
    }
}

// ---------------------------------------------------------------------------
// attn v10 = R5's v6 VERBATIM (last passing attn) + s_setprio around the
// MFMA cluster (T5: pure runtime scheduler hint, correctness-neutral).
// Online softmax, double-buffered p_lds, alpha machinery, pinned 2-deep
// V prefetch with counted vmcnt(4), kh-split, epilogue: all unchanged.
// ---------------------------------------------------------------------------
__global__ __launch_bounds__(512, 4) void attn_kernel(
    const float* __restrict__ ws_st, const float2* __restrict__ ws_cm,
    const _Float16* __restrict__ vtg, float* __restrict__ out)
{
    __shared__ float t_lds[2048];                           // base[d]*log2e, 8 KB
    __shared__ float cm_lds[4096];                          // {c*m, m}[j], 16 KB
    __shared__ __align__(16) _Float16 p_lds[2][2][2][512];  // [buf][rt][ks] 8 KB
    __shared__ __align__(16) float alpha_lds[2][32];
    __shared__ float z_lds[32];
    __shared__ float red_lds[32][264];                      // epilogue only

    const int tid  = threadIdx.x;
    const int lane = tid & 63;
    const int wid  = tid >> 6;                // 0..7
    const int hq   = wid & 3;                 // h quarter
    const int kh   = wid >> 2;                // j half (K-split)
    const int em   = lane & 15;
    const int q4   = lane >> 4;

    const int b  = blockIdx.x & 7;            // XCD-affine batch mapping
    const int i0 = (blockIdx.x >> 3) * 32;

    const int row = tid >> 4;                 // scoring row 0..31 (16 lanes/row)
    const int jg  = tid & 15;                 // 4-j group within chunk
    const int gi  = i0 + row;

    // fragment-tiled V^T base: [b][kc][ks=kh][q4][h=hq*64+ht*16+em][8]
    const _Float16* __restrict__ vb =
        vtg + (size_t)b * 524288 + kh * 8192 + q4 * 2048 + (hq * 64 + em) * 8;

    f32x4 vbA[4], vbB[4];
#define ISSUE_VB(DST, KC) do {                                                  \
        const _Float16* p_ = vb + (size_t)((KC) & 31) * 16384;                  \
        _Pragma("unroll")                                                       \
        for (int ht = 0; ht < 4; ++ht)                                          \
            asm volatile("global_load_dwordx4 %0, %1, off"                      \
                         : "=v"(DST[ht]) : "v"(p_ + ht * 128));                 \
    } while (0)

    ISSUE_VB(vbA, 0);

    // ---- bias table: d==0 ? 0.5 : 1/log2(2+d), scaled by log2(e) ----
#pragma unroll
    for (int v = 0; v < 4; ++v) {
        const int d = tid * 4 + v;
        const float bv = (d == 0) ? 0.5f : 1.0f / __log2f(2.f + (float)d);
        t_lds[d] = bv * 1.44269504088896f;
    }
    // ---- stage ws_cm[b] (2048 float2 = 4096 f32) into LDS ----
#pragma unroll
    for (int v = 0; v < 2; ++v) {
        const int idx = (v * 512 + tid) * 4;
        *(float4*)&cm_lds[idx] =
            *(const float4*)((const float*)(ws_cm + b * 2048) + idx);
    }

    const float sti = ws_st[b * 2048 + gi];

    f32x4 acc[2][4];   // partial PV over this wave's j-half
#pragma unroll
    for (int rt = 0; rt < 2; ++rt)
#pragma unroll
        for (int ht = 0; ht < 4; ++ht) acc[rt][ht] = (f32x4){0.f, 0.f, 0.f, 0.f};
    float m_run = -1e30f;
    float zacc  = 0.f;

    PHASE_BARRIER();   // t_lds / cm_lds visible

    // --- scores(kc) -> P[nbuf], alpha[nbuf]; updates m_run/zacc ---
    auto scores = [&](const int kc, const int nbuf) {
        const int j0 = kc * 64;
        float s_arr[4];
        float mx = -1e30f;
        const float* __restrict__ cmp = &cm_lds[(j0 + jg * 4) * 2];
        const float4 ca = *(const float4*)(cmp + 0);   // {c0*m0,m0,c1*m1,m1}
        const float4 cb = *(const float4*)(cmp + 4);
        {
            const int jj = j0 + jg * 4;
            int d0 = gi - jj;     d0 = d0 < 0 ? -d0 : d0;
            int d1 = gi - jj - 1; d1 = d1 < 0 ? -d1 : d1;
            int d2 = gi - jj - 2; d2 = d2 < 0 ? -d2 : d2;
            int d3 = gi - jj - 3; d3 = d3 < 0 ? -d3 : d3;
            s_arr[0] = (sti * ca.y + ca.x) * t_lds[d0];
            s_arr[1] = (sti * ca.w + ca.z) * t_lds[d1];
            s_arr[2] = (sti * cb.y + cb.x) * t_lds[d2];
            s_arr[3] = (sti * cb.w + cb.z) * t_lds[d3];
            mx = fmaxf(fmaxf(s_arr[0], s_arr[1]), fmaxf(s_arr[2], s_arr[3]));
        }
        // row max across the row's 16 lanes (consecutive, 16-aligned)
        mx = fmaxf(mx, __shfl_xor(mx, 1, 64));
        mx = fmaxf(mx, __shfl_xor(mx, 2, 64));
        mx = fmaxf(mx, __shfl_xor(mx, 4, 64));
        mx = fmaxf(mx, __shfl_xor(mx, 8, 64));

        const float m_new = fmaxf(m_run, mx);
        const float alpha = __builtin_amdgcn_exp2f(m_run - m_new);
        float zl = 0.f;
        half4_t pv;
#pragma unroll
        for (int v = 0; v < 4; ++v) {
            const float p = __builtin_amdgcn_exp2f(s_arr[v] - m_new);
            zl += p;
            pv[v] = (_Float16)p;
        }
        zacc  = zacc * alpha + zl;
        m_run = m_new;

        // P frag-linear: k = jg*4+v; ks=jg>>3; kq=(jg&7)>>1; k8=(jg&1)*4+v
        {
            const int mrow = row & 15;
            const int ks = jg >> 3;
            const int kq = (jg & 7) >> 1;
            const int slot = ((mrow ^ (kq << 1)) + 16 * kq);
            *(half4_t*)&p_lds[nbuf][row >> 4][ks][slot * 8 + (jg & 1) * 4] = pv;
        }
        if (jg == 0) alpha_lds[nbuf][row] = alpha;
    };

    auto rescale = [&](const int cbuf) {
        const float4 a0 = *(const float4*)&alpha_lds[cbuf][q4 * 4];
        const float4 a1 = *(const float4*)&alpha_lds[cbuf][16 + q4 * 4];
        const float ar[2][4] = {{a0.x, a0.y, a0.z, a0.w}, {a1.x, a1.y, a1.z, a1.w}};
        bool upd = false;
#pragma unroll
        for (int rt = 0; rt < 2; ++rt)
#pragma unroll
            for (int r = 0; r < 4; ++r) upd |= (ar[rt][r] != 1.f);
        if (__any(upd)) {
#pragma unroll
            for (int rt = 0; rt < 2; ++rt)
#pragma unroll
                for (int ht = 0; ht < 4; ++ht)
#pragma unroll
                    for (int r = 0; r < 4; ++r)
                        acc[rt][ht][r] *= ar[rt][r];
        }
    };

    // MFMA: this wave's j-half only (K=32); s_setprio around the cluster (T5)
    auto mfma_step = [&](const int cbuf, f32x4 (&vbuf)[4]) {
        const int sl8 = ((em ^ (q4 << 1)) + 16 * q4) * 8;   // read-side swizzle
        const half8 a0 = *(const half8*)&p_lds[cbuf][0][kh][sl8];
        const half8 a1 = *(const half8*)&p_lds[cbuf][1][kh][sl8];
        __builtin_amdgcn_s_setprio(1);
#pragma unroll
        for (int ht = 0; ht < 4; ++ht) {
            const half8 bh = __builtin_bit_cast(half8, vbuf[ht]);
            acc[0][ht] = __builtin_amdgcn_mfma_f32_16x16x32_f16(a0, bh, acc[0][ht], 0, 0, 0);
            acc[1][ht] = __builtin_amdgcn_mfma_f32_16x16x32_f16(a1, bh, acc[1][ht], 0, 0, 0);
        }
        __builtin_amdgcn_s_setprio(0);
    };

    scores(0, 0);
    PHASE_BARRIER();   // P[0]/alpha[0] visible; vbA(0) still in flight

    for (int kc = 0; kc < 32; kc += 2) {
        // ---- even phase: consume buf0/vbA, produce buf1/vbB ----
        ISSUE_VB(vbB, kc + 1);
        rescale(0);
        asm volatile("s_waitcnt vmcnt(4)" ::: "memory");    // vbA arrived
        __builtin_amdgcn_sched_barrier(0);
        mfma_step(0, vbA);
        scores(kc + 1, 1);           // interleaves with MFMA (indep pipes)
        PHASE_BARRIER();

        // ---- odd phase: consume buf1/vbB, produce buf0/vbA ----
        ISSUE_VB(vbA, kc + 2);       // (kc+2)&31 wraps harmlessly at kc=30
        rescale(1);
        asm volatile("s_waitcnt vmcnt(4)" ::: "memory");    // vbB arrived
        __builtin_amdgcn_sched_barrier(0);
        mfma_step(1, vbB);
        if (kc + 2 < 32) scores(kc + 2, 0);
        PHASE_BARRIER();
    }
#undef ISSUE_VB

    // --- Z finalize: reduce the row's 16 lanes, publish ---
    zacc += __shfl_xor(zacc, 1, 64);
    zacc += __shfl_xor(zacc, 2, 64);
    zacc += __shfl_xor(zacc, 4, 64);
    zacc += __shfl_xor(zacc, 8, 64);
    if (jg == 0) z_lds[row] = zacc;

    // --- cross-wave PV reduce: kh=1 partials -> LDS, kh=0 adds ---
    if (kh == 1) {
#pragma unroll
        for (int rt = 0; rt < 2; ++rt)
#pragma unroll
            for (int ht = 0; ht < 4; ++ht)
#pragma unroll
                for (int r = 0; r < 4; ++r)
                    red_lds[rt * 16 + q4 * 4 + r][hq * 64 + ht * 16 + em] = acc[rt][ht][r];
    }
    __syncthreads();   // loop done: full drain is fine here

    if (kh == 0) {
#pragma unroll
        for (int rt = 0; rt < 2; ++rt) {
#pragma unroll
            for (int r = 0; r < 4; ++r) {
                const int orow = rt * 16 + q4 * 4 + r;
                const float rz = 1.f / z_lds[orow];
#pragma unroll
                for (int ht = 0; ht < 4; ++ht) {
                    const float v = acc[rt][ht][r] + red_lds[orow][hq * 64 + ht * 16 + em];
                    out[((size_t)b * 2048 + i0 + orow) * 256 + hq * 64 + ht * 16 + em] = v * rz;
                }
            }
        }
    }
}

// ---------------------------------------------------------------------------
extern "C" void kernel_launch(void* const* d_in, const int* in_sizes, int n_in,
                              void* d_out, int out_size, void* d_ws, size_t ws_size,
                              hipStream_t stream) {
    const float* opin  = (const float*)d_in[0];
    const float* text  = (const float*)d_in[1];
    const int* pos_ids = (const int*)d_in[2];
    const float* Wt    = (const float*)d_in[3];
    const float* bt    = (const float*)d_in[4];
    const float* Wo    = (const float*)d_in[5];
    const float* wa    = (const float*)d_in[6];
    const float* ba    = (const float*)d_in[7];
    float* out         = (float*)d_out;

    // workspace: st (64 KB) | cm (128 KB) | vtg fp16 (8 MB, fragment-tiled)
    float*  ws_st = (float*)d_ws;
    float2* ws_cm = (float2*)((char*)d_ws + 65536);
    _Float16* vtg = (_Float16*)((char*)d_ws + 65536 + 131072);

    prep_kernel<<<512, 256, 0, stream>>>(opin, text, pos_ids, Wt, bt, Wo, wa, ba,
                                         ws_st, ws_cm, vtg);
    attn_kernel<<<512, 512, 0, stream>>>(ws_st, ws_cm, vtg, out);
}

// Round 11
// 137.051 us; speedup vs baseline: 1.0290x; 1.0290x over previous
//
#include <hip/hip_runtime.h>

// Problem: B=8, L=2048, H=256. fp32 in/out.
#define B_ 8
#define L_ 2048
#define H_ 256

typedef _Float16 half8 __attribute__((ext_vector_type(8)));
typedef _Float16 half4_t __attribute__((ext_vector_type(4)));
typedef float f32x4 __attribute__((ext_vector_type(4)));

__device__ __forceinline__ float fast_tanh(float x) {
    const float e2 = __expf(2.f * x);
    return 1.f - 2.f * __builtin_amdgcn_rcpf(e2 + 1.f);
}

// raw barrier: LDS-visibility only (lgkm drain), vmcnt stays in flight.
#define PHASE_BARRIER() do {                                   \
        asm volatile("s_waitcnt lgkmcnt(0)" ::: "memory");     \
        __builtin_amdgcn_s_barrier();                          \
        asm volatile("" ::: "memory");                         \
        __builtin_amdgcn_sched_barrier(0);                     \
    } while (0)

// ---------------------------------------------------------------------------
// 16-lane butterfly reductions on the VALU pipe via DPP (update_dpp builtin).
// __shfl_xor on CDNA is a DS-pipe op (ds_bpermute): 4 serial DS ops per chunk
// were both pipe load AND a ~100-cycle dependent chain. DPP: quad_perm
// [1,0,3,2]=0xB1 (xor1), [2,3,0,1]=0x4E (xor2), row_half_mirror=0x141,
// row_mirror=0x140. At each step the partner lane holds a disjoint aggregate,
// so max/sum are exact (same butterfly invariant as the shfl version).
// ---------------------------------------------------------------------------
__device__ __forceinline__ float dpp_max16(float m) {
    int x;
    x = __builtin_amdgcn_update_dpp(0, __builtin_bit_cast(int, m), 0xB1, 0xf, 0xf, false);
    m = fmaxf(m, __builtin_bit_cast(float, x));
    x = __builtin_amdgcn_update_dpp(0, __builtin_bit_cast(int, m), 0x4E, 0xf, 0xf, false);
    m = fmaxf(m, __builtin_bit_cast(float, x));
    x = __builtin_amdgcn_update_dpp(0, __builtin_bit_cast(int, m), 0x141, 0xf, 0xf, false);
    m = fmaxf(m, __builtin_bit_cast(float, x));
    x = __builtin_amdgcn_update_dpp(0, __builtin_bit_cast(int, m), 0x140, 0xf, 0xf, false);
    m = fmaxf(m, __builtin_bit_cast(float, x));
    return m;
}
__device__ __forceinline__ float dpp_add16(float s) {
    int x;
    x = __builtin_amdgcn_update_dpp(0, __builtin_bit_cast(int, s), 0xB1, 0xf, 0xf, false);
    s += __builtin_bit_cast(float, x);
    x = __builtin_amdgcn_update_dpp(0, __builtin_bit_cast(int, s), 0x4E, 0xf, 0xf, false);
    s += __builtin_bit_cast(float, x);
    x = __builtin_amdgcn_update_dpp(0, __builtin_bit_cast(int, s), 0x141, 0xf, 0xf, false);
    s += __builtin_bit_cast(float, x);
    x = __builtin_amdgcn_update_dpp(0, __builtin_bit_cast(int, s), 0x140, 0xf, 0xf, false);
    s += __builtin_bit_cast(float, x);
    return s;
}

// ---------------------------------------------------------------------------
// prep (R4/R5/R10 verbatim — passing): one block = 64 rows of text (mat=0)
// or opin (mat=1). w_lds double-buffered, pinned W prefetch, raw barriers,
// vtg emitted in MFMA-fragment-tiled layout [b][kc][ks][q4][h][j8].
// ---------------------------------------------------------------------------
__global__ __launch_bounds__(256, 2) void prep_kernel(
    const float* __restrict__ opin, const float* __restrict__ text,
    const int* __restrict__ pos_ids,
    const float* __restrict__ Wt, const float* __restrict__ bt,
    const float* __restrict__ Wo, const float* __restrict__ wa,
    const float* __restrict__ ba,
    float* __restrict__ ws_st, float2* __restrict__ ws_cm,
    _Float16* __restrict__ vtg)
{
    __shared__ __align__(16) _Float16 a_lds[4][8][512];     // 32 KB
    __shared__ __align__(16) _Float16 w_lds[2][16][512];    // 32 KB double-buffered

    const int tid  = threadIdx.x;
    const int lane = tid & 63;
    const int rg   = tid >> 6;
    const int mat  = blockIdx.x & 1;
    const size_t g0 = (size_t)(blockIdx.x >> 1) * 64;

    const float* __restrict__ src = mat ? opin : text;
    const float* __restrict__ W   = mat ? Wo   : Wt;

    f32x4 wregA[8], wregB[8];
#define ISSUE_W(DST, KC) do {                                                   \
        _Pragma("unroll")                                                       \
        for (int p = 0; p < 8; ++p) {                                           \
            const float* p_ = W + (p * 32 + (tid >> 3)) * 256 + (KC) * 32 +     \
                              (tid & 7) * 4;                                    \
            asm volatile("global_load_dwordx4 %0, %1, off"                      \
                         : "=v"(DST[p]) : "v"(p_));                             \
        }                                                                       \
    } while (0)

    ISSUE_W(wregA, 0);

    for (int v = 0; v < 16; ++v) {
        const int idx = v * 256 + tid;
        const int row = idx >> 6;
        const int k   = (idx & 63) * 4;
        const float4 f = *(const float4*)(src + (g0 + row) * 256 + k);
        half4_t h = { (_Float16)f.x, (_Float16)f.y, (_Float16)f.z, (_Float16)f.w };
        const int off = ((row & 15) + 16 * ((k >> 3) & 3)) * 8 + (k & 7);
        *(half4_t*)&a_lds[row >> 4][k >> 5][off] = h;
    }
    PHASE_BARRIER();

    f32x4 acc[16];
#pragma unroll
    for (int nt = 0; nt < 16; ++nt) acc[nt] = (f32x4){0.f, 0.f, 0.f, 0.f};

    auto wbody = [&](const int kc, f32x4 (&cur)[8], f32x4 (&nxt)[8]) {
        asm volatile("s_waitcnt vmcnt(0)" ::: "memory");
        __builtin_amdgcn_sched_barrier(0);
        if (kc < 7) ISSUE_W(nxt, kc + 1);
#pragma unroll
        for (int p = 0; p < 8; ++p) {
            const int n = p * 32 + (tid >> 3);
            const int k = (tid & 7) * 4;
            const float4 f = __builtin_bit_cast(float4, cur[p]);
            half4_t h = { (_Float16)f.x, (_Float16)f.y, (_Float16)f.z, (_Float16)f.w };
            const int off = ((n & 15) + 16 * (k >> 3)) * 8 + (k & 7);
            *(half4_t*)&w_lds[kc & 1][n >> 4][off] = h;
        }
        PHASE_BARRIER();
        const half8 afrag = *(const half8*)&a_lds[rg][kc][lane * 8];
#pragma unroll
        for (int nt = 0; nt < 16; ++nt) {
            const half8 bfrag = *(const half8*)&w_lds[kc & 1][nt][lane * 8];
            acc[nt] = __builtin_amdgcn_mfma_f32_16x16x32_f16(afrag, bfrag, acc[nt], 0, 0, 0);
        }
    };
    for (int kc = 0; kc < 8; kc += 2) {
        wbody(kc,     wregA, wregB);
        wbody(kc + 1, wregB, wregA);
    }
#undef ISSUE_W

    const int em = lane & 15, q = lane >> 4;
    float rowsum[4] = {0.f, 0.f, 0.f, 0.f};
#pragma unroll
    for (int nt = 0; nt < 16; ++nt) {
        const int col  = nt * 16 + em;
        const float btv = mat ? 0.f : bt[col];
        const float wav = wa[mat * 256 + col];
#pragma unroll
        for (int r = 0; r < 4; ++r)
            rowsum[r] += fast_tanh(acc[nt][r] + btv) * wav;
    }
#pragma unroll
    for (int r = 0; r < 4; ++r) {
        float s = rowsum[r];
        s += __shfl_xor(s, 1, 64);
        s += __shfl_xor(s, 2, 64);
        s += __shfl_xor(s, 4, 64);
        s += __shfl_xor(s, 8, 64);
        if (em == 0) {
            const size_t grow = g0 + rg * 16 + q * 4 + r;
            if (mat == 0) {
                ws_st[grow] = s;
            } else {
                const int p = pos_ids[grow];
                const bool isop = (p==19)|(p==20)|(p==21)|(p==33)|(p==34)|(p==35)|((p>=41)&(p<=46));
                const float mult = isop ? 8.f : 1.f;
                const float c = s + ba[0];
                ws_cm[grow] = make_float2(c * mult, mult);
            }
        }
    }

    if (mat == 1) {
        const int h = tid;
        const size_t b = g0 >> 11;
        const int kcj = (int)((g0 & 2047) >> 6);
        const int kc = h >> 5, kq = (h >> 3) & 3, jh = h & 7;
        _Float16 vals[64];
#pragma unroll
        for (int r = 0; r < 64; ++r)
            vals[r] = a_lds[r >> 4][kc][((r & 15) + 16 * kq) * 8 + jh];
        _Float16* dst = vtg + ((size_t)b * 32 + kcj) * 16384 + h * 8;
#pragma unroll
        for (int w = 0; w < 8; ++w)
            *(half8*)(dst + w * 2048) = *(half8*)&vals[w * 8];
    }
}

// ---------------------------------------------------------------------------
// attn v11 = v10 (PASSING, 44.0us) with two DS-pipe-load reductions:
//  (1) 16-lane max-reduce and z-sum moved from __shfl_xor (DS pipe, serial
//      ~100cy chain) to DPP butterflies on the VALU pipe (exact same values).
//  (2) cm_lds de-interleaved into cmc (c*m) / cmm (m): score reads become
//      bank-balanced b128 at 16B/lane (v10's {c,m} pairs = 32B/lane stride,
//      half the banks idle -> main source of the 2.88M conflict cycles).
// Everything else (online softmax, double-buffered p_lds, alpha machinery,
// pinned vmcnt(4) V pipeline, kh-split, setprio, epilogue) is v10 verbatim.
// ---------------------------------------------------------------------------
__global__ __launch_bounds__(512, 4) void attn_kernel(
    const float* __restrict__ ws_st, const float2* __restrict__ ws_cm,
    const _Float16* __restrict__ vtg, float* __restrict__ out)
{
    __shared__ float t_lds[2048];                           // base[d]*log2e, 8 KB
    __shared__ __align__(16) float cmc_lds[2048];           // c*m per j, 8 KB
    __shared__ __align__(16) float cmm_lds[2048];           // m   per j, 8 KB
    __shared__ __align__(16) _Float16 p_lds[2][2][2][512];  // [buf][rt][ks] 8 KB
    __shared__ __align__(16) float alpha_lds[2][32];
    __shared__ float z_lds[32];
    __shared__ float red_lds[32][264];                      // epilogue only

    const int tid  = threadIdx.x;
    const int lane = tid & 63;
    const int wid  = tid >> 6;                // 0..7
    const int hq   = wid & 3;                 // h quarter
    const int kh   = wid >> 2;                // j half (K-split)
    const int em   = lane & 15;
    const int q4   = lane >> 4;

    const int b  = blockIdx.x & 7;            // XCD-affine batch mapping
    const int i0 = (blockIdx.x >> 3) * 32;

    const int row = tid >> 4;                 // scoring row 0..31 (16 lanes/row)
    const int jg  = tid & 15;                 // 4-j group within chunk
    const int gi  = i0 + row;

    // fragment-tiled V^T base: [b][kc][ks=kh][q4][h=hq*64+ht*16+em][8]
    const _Float16* __restrict__ vb =
        vtg + (size_t)b * 524288 + kh * 8192 + q4 * 2048 + (hq * 64 + em) * 8;

    f32x4 vbA[4], vbB[4];
#define ISSUE_VB(DST, KC) do {                                                  \
        const _Float16* p_ = vb + (size_t)((KC) & 31) * 16384;                  \
        _Pragma("unroll")                                                       \
        for (int ht = 0; ht < 4; ++ht)                                          \
            asm volatile("global_load_dwordx4 %0, %1, off"                      \
                         : "=v"(DST[ht]) : "v"(p_ + ht * 128));                 \
    } while (0)

    ISSUE_VB(vbA, 0);

    // ---- bias table: d==0 ? 0.5 : 1/log2(2+d), scaled by log2(e) ----
#pragma unroll
    for (int v = 0; v < 4; ++v) {
        const int d = tid * 4 + v;
        const float bv = (d == 0) ? 0.5f : 1.0f / __log2f(2.f + (float)d);
        t_lds[d] = bv * 1.44269504088896f;
    }
    // ---- stage ws_cm[b], de-interleaved: cmc[j]=c*m, cmm[j]=m ----
#pragma unroll
    for (int v = 0; v < 2; ++v) {
        const int idx4 = v * 512 + tid;              // float4 index; j = idx4*2
        const float4 f =
            *(const float4*)((const float*)(ws_cm + b * 2048) + idx4 * 4);
        const int j = idx4 * 2;
        cmc_lds[j]     = f.x;  cmm_lds[j]     = f.y;
        cmc_lds[j + 1] = f.z;  cmm_lds[j + 1] = f.w;
    }

    const float sti = ws_st[b * 2048 + gi];

    f32x4 acc[2][4];   // partial PV over this wave's j-half
#pragma unroll
    for (int rt = 0; rt < 2; ++rt)
#pragma unroll
        for (int ht = 0; ht < 4; ++ht) acc[rt][ht] = (f32x4){0.f, 0.f, 0.f, 0.f};
    float m_run = -1e30f;
    float zacc  = 0.f;

    PHASE_BARRIER();   // t_lds / cmc/cmm visible

    // --- scores(kc) -> P[nbuf], alpha[nbuf]; updates m_run/zacc ---
    auto scores = [&](const int kc, const int nbuf) {
        const int j0 = kc * 64;
        float s_arr[4];
        float mx = -1e30f;
        const float4 cv = *(const float4*)&cmc_lds[j0 + jg * 4];  // c*m x4
        const float4 mv = *(const float4*)&cmm_lds[j0 + jg * 4];  // m   x4
        {
            const int jj = j0 + jg * 4;
            int d0 = gi - jj;     d0 = d0 < 0 ? -d0 : d0;
            int d1 = gi - jj - 1; d1 = d1 < 0 ? -d1 : d1;
            int d2 = gi - jj - 2; d2 = d2 < 0 ? -d2 : d2;
            int d3 = gi - jj - 3; d3 = d3 < 0 ? -d3 : d3;
            s_arr[0] = (sti * mv.x + cv.x) * t_lds[d0];
            s_arr[1] = (sti * mv.y + cv.y) * t_lds[d1];
            s_arr[2] = (sti * mv.z + cv.z) * t_lds[d2];
            s_arr[3] = (sti * mv.w + cv.w) * t_lds[d3];
            mx = fmaxf(fmaxf(s_arr[0], s_arr[1]), fmaxf(s_arr[2], s_arr[3]));
        }
        // row max across the row's 16 lanes — VALU DPP butterfly (no DS ops)
        mx = dpp_max16(mx);

        const float m_new = fmaxf(m_run, mx);
        const float alpha = __builtin_amdgcn_exp2f(m_run - m_new);
        float zl = 0.f;
        half4_t pv;
#pragma unroll
        for (int v = 0; v < 4; ++v) {
            const float p = __builtin_amdgcn_exp2f(s_arr[v] - m_new);
            zl += p;
            pv[v] = (_Float16)p;
        }
        zacc  = zacc * alpha + zl;
        m_run = m_new;

        // P frag-linear: k = jg*4+v; ks=jg>>3; kq=(jg&7)>>1; k8=(jg&1)*4+v
        {
            const int mrow = row & 15;
            const int ks = jg >> 3;
            const int kq = (jg & 7) >> 1;
            const int slot = ((mrow ^ (kq << 1)) + 16 * kq);
            *(half4_t*)&p_lds[nbuf][row >> 4][ks][slot * 8 + (jg & 1) * 4] = pv;
        }
        if (jg == 0) alpha_lds[nbuf][row] = alpha;
    };

    auto rescale = [&](const int cbuf) {
        const float4 a0 = *(const float4*)&alpha_lds[cbuf][q4 * 4];
        const float4 a1 = *(const float4*)&alpha_lds[cbuf][16 + q4 * 4];
        const float ar[2][4] = {{a0.x, a0.y, a0.z, a0.w}, {a1.x, a1.y, a1.z, a1.w}};
        bool upd = false;
#pragma unroll
        for (int rt = 0; rt < 2; ++rt)
#pragma unroll
            for (int r = 0; r < 4; ++r) upd |= (ar[rt][r] != 1.f);
        if (__any(upd)) {
#pragma unroll
            for (int rt = 0; rt < 2; ++rt)
#pragma unroll
                for (int ht = 0; ht < 4; ++ht)
#pragma unroll
                    for (int r = 0; r < 4; ++r)
                        acc[rt][ht][r] *= ar[rt][r];
        }
    };

    // MFMA: this wave's j-half only (K=32); s_setprio around the cluster (T5)
    auto mfma_step = [&](const int cbuf, f32x4 (&vbuf)[4]) {
        const int sl8 = ((em ^ (q4 << 1)) + 16 * q4) * 8;   // read-side swizzle
        const half8 a0 = *(const half8*)&p_lds[cbuf][0][kh][sl8];
        const half8 a1 = *(const half8*)&p_lds[cbuf][1][kh][sl8];
        __builtin_amdgcn_s_setprio(1);
#pragma unroll
        for (int ht = 0; ht < 4; ++ht) {
            const half8 bh = __builtin_bit_cast(half8, vbuf[ht]);
            acc[0][ht] = __builtin_amdgcn_mfma_f32_16x16x32_f16(a0, bh, acc[0][ht], 0, 0, 0);
            acc[1][ht] = __builtin_amdgcn_mfma_f32_16x16x32_f16(a1, bh, acc[1][ht], 0, 0, 0);
        }
        __builtin_amdgcn_s_setprio(0);
    };

    scores(0, 0);
    PHASE_BARRIER();   // P[0]/alpha[0] visible; vbA(0) still in flight

    for (int kc = 0; kc < 32; kc += 2) {
        // ---- even phase: consume buf0/vbA, produce buf1/vbB ----
        ISSUE_VB(vbB, kc + 1);
        rescale(0);
        asm volatile("s_waitcnt vmcnt(4)" ::: "memory");    // vbA arrived
        __builtin_amdgcn_sched_barrier(0);
        mfma_step(0, vbA);
        scores(kc + 1, 1);           // interleaves with MFMA (indep pipes)
        PHASE_BARRIER();

        // ---- odd phase: consume buf1/vbB, produce buf0/vbA ----
        ISSUE_VB(vbA, kc + 2);       // (kc+2)&31 wraps harmlessly at kc=30
        rescale(1);
        asm volatile("s_waitcnt vmcnt(4)" ::: "memory");    // vbB arrived
        __builtin_amdgcn_sched_barrier(0);
        mfma_step(1, vbB);
        if (kc + 2 < 32) scores(kc + 2, 0);
        PHASE_BARRIER();
    }
#undef ISSUE_VB

    // --- Z finalize: 16-lane sum via VALU DPP butterfly, publish ---
    zacc = dpp_add16(zacc);
    if (jg == 0) z_lds[row] = zacc;

    // --- cross-wave PV reduce: kh=1 partials -> LDS, kh=0 adds ---
    if (kh == 1) {
#pragma unroll
        for (int rt = 0; rt < 2; ++rt)
#pragma unroll
            for (int ht = 0; ht < 4; ++ht)
#pragma unroll
                for (int r = 0; r < 4; ++r)
                    red_lds[rt * 16 + q4 * 4 + r][hq * 64 + ht * 16 + em] = acc[rt][ht][r];
    }
    __syncthreads();   // loop done: full drain is fine here

    if (kh == 0) {
#pragma unroll
        for (int rt = 0; rt < 2; ++rt) {
#pragma unroll
            for (int r = 0; r < 4; ++r) {
                const int orow = rt * 16 + q4 * 4 + r;
                const float rz = 1.f / z_lds[orow];
#pragma unroll
                for (int ht = 0; ht < 4; ++ht) {
                    const float v = acc[rt][ht][r] + red_lds[orow][hq * 64 + ht * 16 + em];
                    out[((size_t)b * 2048 + i0 + orow) * 256 + hq * 64 + ht * 16 + em] = v * rz;
                }
            }
        }
    }
}

// ---------------------------------------------------------------------------
extern "C" void kernel_launch(void* const* d_in, const int* in_sizes, int n_in,
                              void* d_out, int out_size, void* d_ws, size_t ws_size,
                              hipStream_t stream) {
    const float* opin  = (const float*)d_in[0];
    const float* text  = (const float*)d_in[1];
    const int* pos_ids = (const int*)d_in[2];
    const float* Wt    = (const float*)d_in[3];
    const float* bt    = (const float*)d_in[4];
    const float* Wo    = (const float*)d_in[5];
    const float* wa    = (const float*)d_in[6];
    const float* ba    = (const float*)d_in[7];
    float* out         = (float*)d_out;

    // workspace: st (64 KB) | cm (128 KB) | vtg fp16 (8 MB, fragment-tiled)
    float*  ws_st = (float*)d_ws;
    float2* ws_cm = (float2*)((char*)d_ws + 65536);
    _Float16* vtg = (_Float16*)((char*)d_ws + 65536 + 131072);

    prep_kernel<<<512, 256, 0, stream>>>(opin, text, pos_ids, Wt, bt, Wo, wa, ba,
                                         ws_st, ws_cm, vtg);
    attn_kernel<<<512, 512, 0, stream>>>(ws_st, ws_cm, vtg, out);
}